// Round 13
// baseline (334.047 us; speedup 1.0000x reference)
//
#include <hip/hip_runtime.h>
#include <math.h>

// ---------------------------------------------------------------------------
// Dual CTC loss forward, linear-probability fp64 recursion, beta-normalized
// B/L split form (validated R6).
// R21: BAND-SPLIT phoneme chain — two waves per chain, LDS ring handoff.
//  R20 null: gfx950 has NO packed f64 (isa ref lists pk f32/f16 only) — the
//  double2 step scalarized to the same 16 f64 ops. Per-wave issue floor
//  stands. Remaining lever: the recursion's cross-pair dependency is
//  one-directional (pair p needs only L[p-1]), so split the 201-pair band
//  across 2 waves (w0: pairs 0-99, w1: pairs 100-200, both P=2). w0 streams
//  freely, publishing L[99]+K each step into a 2048-entry LDS ring (never
//  wraps, never stalls); w1 trails ~7 steps polling a workgroup-scope LDS
//  counter (intra-CU — none of R10/R11's agent-scope poison). Per-wave step
//  issue: 16 f64 -> 10 f64 ops.
//  Numerics: per-wave renorm frames K0,K1; boundary rescaled by exact 2^
//  (K1-K0) (clamped [-1022,512], self-correcting); w1 adopts w0's frame
//  while its band is empty (emax==0); readout recombines frames log-domain.
//  All scalings exact powers of 2.
//  error task: unchanged full-depth inline-f chain (blocks 0-31, wave 0).
// Falls back to the R2 proven path if ws too small.
// ---------------------------------------------------------------------------

static constexpr float  LOG2E = 1.4426950408889634f;
static constexpr double LN2D  = 0.6931471805599453;
static constexpr int GROWS = 2032;  // padded rows per chain

#define DPP_WAVE_SHR1   0x138
#define DPP_ROW_SHR(n)  (0x110 | (n))
#define DPP_ROW_BCAST15 0x142
#define DPP_ROW_BCAST31 0x143

__device__ __forceinline__ float fexp2(float x) {
  return __builtin_amdgcn_exp2f(x);
}
__device__ __forceinline__ float flog2(float x) {
  return __builtin_amdgcn_logf(x);
}

// prev-lane value (lane i gets lane i-1; lane 0 gets 0.0) — pure VALU
__device__ __forceinline__ double dpp_shr1_f64(double x) {
  int lo = __double2loint(x), hi = __double2hiint(x);
  lo = __builtin_amdgcn_update_dpp(0, lo, DPP_WAVE_SHR1, 0xf, 0xf, true);
  hi = __builtin_amdgcn_update_dpp(0, hi, DPP_WAVE_SHR1, 0xf, 0xf, true);
  return __hiloint2double(hi, lo);
}

__device__ __forceinline__ int imax2(int a, int b) { return a > b ? a : b; }

__device__ __forceinline__ int wave_imax(int v) {
  v = imax2(v, __builtin_amdgcn_update_dpp(0, v, DPP_ROW_SHR(1), 0xf, 0xf, true));
  v = imax2(v, __builtin_amdgcn_update_dpp(0, v, DPP_ROW_SHR(2), 0xf, 0xf, true));
  v = imax2(v, __builtin_amdgcn_update_dpp(0, v, DPP_ROW_SHR(4), 0xf, 0xf, true));
  v = imax2(v, __builtin_amdgcn_update_dpp(0, v, DPP_ROW_SHR(8), 0xf, 0xf, true));
  v = imax2(v, __builtin_amdgcn_update_dpp(0, v, DPP_ROW_BCAST15, 0xf, 0xf, true));
  v = imax2(v, __builtin_amdgcn_update_dpp(0, v, DPP_ROW_BCAST31, 0xf, 0xf, true));
  return __builtin_amdgcn_readlane(v, 63);
}

// wait lgkmcnt(0) only (vmcnt=63, exp=7): gfx9 encode 0xC07F = 49279
__device__ __forceinline__ void wait_lgkm0() {
  __builtin_amdgcn_sched_barrier(0);
  __builtin_amdgcn_s_waitcnt(49279);
  __builtin_amdgcn_sched_barrier(0);
}

// ========================= fast path =======================================

// Slim gather (R13/R18-proven): phoneme r-values + both Lpb arrays + out=0.
__global__ __launch_bounds__(256) void gather_ph_kernel(
    const float* __restrict__ ph_logits, const float* __restrict__ err_logits,
    const int* __restrict__ ph_tgt,
    float* __restrict__ Gph, float* __restrict__ Lpb_ph,
    float* __restrict__ Lpb_er, float* __restrict__ out) {
  const int bx = blockIdx.x, b = blockIdx.y;
  const int tid = threadIdx.x;
  const int lane = tid & 63, wv = tid >> 6;

  if (bx == 0 && b == 0 && tid == 0) *out = 0.f;  // chain kernel comes after

  // ---- error Lpb (wave 0, lanes 0..31) ----
  if (wv == 0 && lane < 32) {
    const int t = bx * 32 + lane;
    if (t < 2000) {
      const float4 v = *(const float4*)(err_logits + ((size_t)b * 2000 + t) * 4);
      const float z0 = v.x * LOG2E;
      const float s = fexp2(z0) + fexp2(v.y * LOG2E) + fexp2(v.z * LOG2E) +
                      fexp2(v.w * LOG2E);
      Lpb_er[(size_t)b * GROWS + t] = z0 - flog2(s);
    }
  }

  // ---- phoneme: 8 rows per wave ----
  const int* tb = ph_tgt + b * 200;
  int idx[4];
  float msk[4];
#pragma unroll
  for (int k = 0; k < 4; ++k) {
    const int si = lane * 4 + k;
    const int cls = (si < 200) ? tb[si] : 0;
    idx[k] = cls << 2;
    msk[k] = (si < 200) ? 1.0f : 0.0f;
  }
  const int t0 = (bx * 4 + wv) * 8;
  float z[8], e[8], s[8];
#pragma unroll
  for (int u = 0; u < 8; ++u) {
    const int t = t0 + u;
    const int tc = (t < 2000) ? t : 1999;
    z[u] = ph_logits[((size_t)b * 2000 + tc) * 64 + lane] * LOG2E;
    e[u] = fexp2(z[u]);
    s[u] = e[u];
  }
#pragma unroll
  for (int off = 32; off >= 1; off >>= 1) {
#pragma unroll
    for (int u = 0; u < 8; ++u) s[u] += __shfl_xor(s[u], off, 64);
  }
#pragma unroll
  for (int u = 0; u < 8; ++u) {
    const int t = t0 + u;
    if (t < 2000) {
      const float e0 = __int_as_float(
          __builtin_amdgcn_readlane(__float_as_int(e[u]), 0));
      const float inv0 = 1.0f / e0;
      float o[4];
#pragma unroll
      for (int k = 0; k < 4; ++k) {
        const float v = __int_as_float(
            __builtin_amdgcn_ds_bpermute(idx[k], __float_as_int(e[u])));
        o[k] = msk[k] * v * inv0;
      }
      *(float4*)(Gph + ((size_t)b * GROWS + t) * 256 + lane * 4) =
          make_float4(o[0], o[1], o[2], o[3]);
      if (lane == 0)  // lane 0's z is z0*log2e
        Lpb_ph[(size_t)b * GROWS + t] = z[u] - flog2(s[u]);
    }
  }
}

template <int P> struct RowP { float v[P]; };

__device__ __forceinline__ float2 ld2(const float* p) {
  return *(const float2*)p;
}

// ---- scalar renorm/step for error path (P=1, R18-proven) ----
template <int P>
__device__ __forceinline__ void bl_renorm(double (&B)[P], double (&L)[P],
                                          int& K) {
  double mm = B[0];
#pragma unroll
  for (int k = 0; k < P; ++k) mm = fmax(fmax(mm, B[k]), L[k]);
  const int ex = (__double2hiint(mm) >> 20) & 0x7ff;
  const int emax = wave_imax(ex);
  if (emax > 0) {
    int d = 1523 - emax;            // pin band max to ~2^500
    if (d > 1023) d = 1023;
    if (d < -1022) d = -1022;
    const double sc = __hiloint2double((d + 1023) << 20, 0);
#pragma unroll
    for (int k = 0; k < P; ++k) { B[k] *= sc; L[k] *= sc; }
    K += d;
  }
}

template <int P>
__device__ __forceinline__ void bl_step(double (&B)[P], double (&L)[P],
                                        const double (&skipm)[P],
                                        const RowP<P>& f) {
  const double Lm1 = dpp_shr1_f64(L[P - 1]);
  double nB[P], nL[P];
#pragma unroll
  for (int k = 0; k < P; ++k) {
    const double Lp = (k >= 1) ? L[k - 1] : Lm1;
    nB[k] = B[k] + Lp;
    nL[k] = (double)f.v[k] * fma(skipm[k], Lp, B[k] + L[k]);
  }
#pragma unroll
  for (int k = 0; k < P; ++k) { B[k] = nB[k]; L[k] = nL[k]; }
}

// ---- P=2 renorm (returns emax for the frame-adoption check) ----
__device__ __forceinline__ int bl_renorm2(double& B0, double& B1,
                                          double& L0, double& L1, int& K) {
  const double mm = fmax(fmax(B0, B1), fmax(L0, L1));
  const int ex = (__double2hiint(mm) >> 20) & 0x7ff;
  const int emax = wave_imax(ex);
  if (emax > 0) {
    int d = 1523 - emax;            // pin band max to ~2^500
    if (d > 1023) d = 1023;
    if (d < -1022) d = -1022;
    const double sc = __hiloint2double((d + 1023) << 20, 0);
    B0 *= sc; B1 *= sc; L0 *= sc; L1 *= sc;
    K += d;
  }
  return emax;
}

// ---- P=2 step. hasInj: lane 0's L[p-1] comes from the LDS ring ----
__device__ __forceinline__ void bl_step2(double& B0, double& B1,
                                         double& L0, double& L1,
                                         double sk0, double sk1, float2 f,
                                         double inj, bool hasInj, int lane) {
  double Lm1 = dpp_shr1_f64(L1);
  if (hasInj) Lm1 = (lane == 0) ? inj : Lm1;
  const double Lp0 = Lm1, Lp1 = L0;
  const double nB0 = B0 + Lp0;
  const double nB1 = B1 + Lp1;
  const double t0 = fma(sk0, Lp0, B0 + L0);
  const double t1 = fma(sk1, Lp1, B1 + L1);
  L0 = (double)f.x * t0;
  L1 = (double)f.y * t1;
  B0 = nB0;
  B1 = nB1;
}

// spb = sum_{t<len} Lpb[t], lane-parallel, x8 ILP
__device__ __forceinline__ float spb_sum(const float* __restrict__ Lpb,
                                         int len, int lane) {
  float spb = 0.f;
  for (int t0 = lane; t0 < len; t0 += 512) {
#pragma unroll
    for (int u = 0; u < 8; ++u) {
      const int t = t0 + u * 64;
      const int tc = (t < len) ? t : 0;        // always-valid address
      const float v = Lpb[tc];
      spb += (t < len) ? v : 0.0f;             // cndmask, no branch
    }
  }
#pragma unroll
  for (int off = 32; off >= 1; off >>= 1) spb += __shfl_xor(spb, off, 64);
  return spb;
}

// ---------------------------------------------------------------------------
// Chain kernel: 64 blocks x 128 thr.
//  blk [0,32):  error FULL chain on wave 0 (R18-proven); wave 1 exits.
//  blk [32,64): phoneme band-split: wave 0 pairs 0-99, wave 1 pairs 100-200.
// ---------------------------------------------------------------------------
__global__ __launch_bounds__(128) void ctc_chains_split_kernel(
    const float* __restrict__ Gph, const float* __restrict__ err_logits,
    const int* __restrict__ ph_tgt, const int* __restrict__ err_tgt,
    const int* __restrict__ err_il, const int* __restrict__ ph_il,
    const int* __restrict__ err_tl, const int* __restrict__ ph_tl,
    const float* __restrict__ Lpb_ph, const float* __restrict__ Lpb_er,
    float* __restrict__ out) {
  __shared__ double ring_v[2048];
  __shared__ int    ring_k[2048];
  __shared__ int    cnt;
  __shared__ double saB[256], saL[256];
  __shared__ int    Kw2[2];
  const int blk = blockIdx.x;

  if (blk < 32) {
    // ================= error: full chain, P=1, inline f, wave 0 ===========
    if (threadIdx.x >= 64) return;
    const int lane = threadIdx.x;
    constexpr int S = 50;
    const int c = blk;
    const int* tb = err_tgt + c * 50;
    int len = err_il[c]; if (len > 2000) len = 2000;
    const int tl = err_tl[c];
    const float4* zr = (const float4*)(err_logits + (size_t)c * 2000 * 4);

    const float spb = spb_sum(Lpb_er + (size_t)c * GROWS, len, lane);
    const int c1 = tb[(lane < S) ? lane : (S - 1)];
    const float fmask = (lane < S) ? 1.0f : 0.0f;
    double skipm[1];
    skipm[0] = (lane >= 1 && lane < S && tb[lane] != tb[lane - 1]) ? 1.0 : 0.0;

    double B[1], L[1];
    B[0] = 0.0; L[0] = 0.0;
    {
      const float4 q0 = zr[0];
      const int c0 = tb[0];
      const float zc = (c0 == 1) ? q0.y : (c0 == 2) ? q0.z : q0.w;
      if (lane == 0) {
        B[0] = 1.0;
        L[0] = (double)fexp2((zc - q0.x) * LOG2E);
      }
    }
    int K = 0;

    const int nsteps = len - 1;          // rows 1..len-1
    const int ng = nsteps / 8;
    float4 bufA[8], bufB[8];
    if (ng >= 1) {
#pragma unroll
      for (int u = 0; u < 8; ++u) bufA[u] = zr[1 + u];
    }
    if (ng >= 2) {
#pragma unroll
      for (int u = 0; u < 8; ++u) bufB[u] = zr[9 + u];
    }
    int g = 0;
    for (; g + 2 <= ng; g += 2) {
      bl_renorm<1>(B, L, K);
      {
        const int gn = (g + 2 < ng) ? (g + 2) : 0;  // clamp re-reads rows 1..8
        const float4* nx = zr + 1 + gn * 8;
#pragma unroll
        for (int u = 0; u < 8; ++u) {
          RowP<1> f;
          const float4 q = bufA[u];
          const float zc = (c1 == 1) ? q.y : (c1 == 2) ? q.z : q.w;
          f.v[0] = fmask * fexp2((zc - q.x) * LOG2E);
          bl_step<1>(B, L, skipm, f);
          bufA[u] = nx[u];
        }
      }
      bl_renorm<1>(B, L, K);
      {
        const int gn = (g + 3 < ng) ? (g + 3) : 0;
        const float4* nx = zr + 1 + gn * 8;
#pragma unroll
        for (int u = 0; u < 8; ++u) {
          RowP<1> f;
          const float4 q = bufB[u];
          const float zc = (c1 == 1) ? q.y : (c1 == 2) ? q.z : q.w;
          f.v[0] = fmask * fexp2((zc - q.x) * LOG2E);
          bl_step<1>(B, L, skipm, f);
          bufB[u] = nx[u];
        }
      }
    }
    if (g < ng) {
      bl_renorm<1>(B, L, K);
#pragma unroll
      for (int u = 0; u < 8; ++u) {
        RowP<1> f;
        const float4 q = bufA[u];
        const float zc = (c1 == 1) ? q.y : (c1 == 2) ? q.z : q.w;
        f.v[0] = fmask * fexp2((zc - q.x) * LOG2E);
        bl_step<1>(B, L, skipm, f);
      }
      ++g;
    }
    {  // tail rows 1+ng*8 .. nsteps (<=7)
      const int tstart = 1 + ng * 8;
      float4 bufT[7];
#pragma unroll
      for (int u = 0; u < 7; ++u) {
        int t = tstart + u;
        if (t > nsteps) t = (nsteps > 0) ? nsteps : 1;
        bufT[u] = zr[t];
      }
#pragma unroll
      for (int u = 0; u < 7; ++u) {
        if (tstart + u <= nsteps) {
          if (u == 0) bl_renorm<1>(B, L, K);
          RowP<1> f;
          const float4 q = bufT[u];
          const float zc = (c1 == 1) ? q.y : (c1 == 2) ? q.z : q.w;
          f.v[0] = fmask * fexp2((zc - q.x) * LOG2E);
          bl_step<1>(B, L, skipm, f);
        }
      }
    }

    // readout: alpha[2tl-1] = L[tl-1], alpha[2tl] = B[tl]
    saB[lane] = B[0];
    saL[lane] = L[0];
    wait_lgkm0();
    if (lane == 0) {
      const double a = saL[tl - 1] + saB[tl];
      float loss = (float)((double)K * LN2D - log(a) - (double)spb * LN2D);
      if (!(loss < 1e29f)) loss = 0.f;  // zero_infinity
      atomicAdd(out, loss / ((float)tl * 32.0f));
    }
    return;
  }

  // ================= phoneme: band-split, 2 waves, P=2 =================
  constexpr int S = 200, LSTRIDE = 256;
  const int b = blk - 32;
  const int wv = threadIdx.x >> 6;
  const int lane = threadIdx.x & 63;
  const int* tb = ph_tgt + b * 200;
  int len = ph_il[b]; if (len > 2000) len = 2000;
  const int tl = ph_tl[b];
  const float* Glab = Gph + (size_t)b * GROWS * 256;

  const int cbase = wv * 100 + lane * 2;      // pair indices p0=cbase, p1=+1
  const float* gp = Glab + cbase;
  const int p0 = cbase, p1 = cbase + 1;
  const double sk0 =
      (p0 >= 1 && p0 < S && tb[p0] != tb[p0 - 1]) ? 1.0 : 0.0;
  const double sk1 = (p1 < S && tb[p1] != tb[p1 - 1]) ? 1.0 : 0.0;

  if (threadIdx.x == 0) { cnt = 0; ring_v[0] = 0.0; ring_k[0] = 0; }
  __syncthreads();

  const int nsteps = len - 1;
  float spb = 0.f;

  if (wv == 0) {
    // -------- wave 0: pairs 0..99 (lanes 50-63 compute harmless dups) -----
    double B0 = 0.0, B1 = 0.0, L0 = 0.0, L1 = 0.0;
    if (lane == 0) { B0 = 1.0; L0 = (double)Glab[0]; }
    int K = 0;

    const int ng = nsteps / 16;
    float2 bufA[16], bufB[16];
    if (ng >= 1) {
      const float* rb = gp + (size_t)1 * LSTRIDE;
#pragma unroll
      for (int u = 0; u < 16; ++u) bufA[u] = ld2(rb + (size_t)u * LSTRIDE);
    }
    if (ng >= 2) {
      const float* rb = gp + (size_t)17 * LSTRIDE;
#pragma unroll
      for (int u = 0; u < 16; ++u) bufB[u] = ld2(rb + (size_t)u * LSTRIDE);
    }

    int t = 1;
    int g = 0;
    for (; g + 2 <= ng; g += 2) {
      bl_renorm2(B0, B1, L0, L1, K);
      {
        const int gn = (g + 2 < ng) ? (g + 2) : 0;  // clamp: rows 1..16
        const float* nx = gp + (size_t)(1 + gn * 16) * LSTRIDE;
#pragma unroll
        for (int u = 0; u < 16; ++u) {
          bl_step2(B0, B1, L0, L1, sk0, sk1, bufA[u], 0.0, false, lane);
          if (lane == 49) {        // publish L[99] + K, then release counter
            ring_v[t] = L1;
            ring_k[t] = K;
            __hip_atomic_store(&cnt, t, __ATOMIC_RELEASE,
                               __HIP_MEMORY_SCOPE_WORKGROUP);
          }
          bufA[u] = ld2(nx + (size_t)u * LSTRIDE);
          ++t;
        }
      }
      bl_renorm2(B0, B1, L0, L1, K);
      {
        const int gn = (g + 3 < ng) ? (g + 3) : 0;
        const float* nx = gp + (size_t)(1 + gn * 16) * LSTRIDE;
#pragma unroll
        for (int u = 0; u < 16; ++u) {
          bl_step2(B0, B1, L0, L1, sk0, sk1, bufB[u], 0.0, false, lane);
          if (lane == 49) {
            ring_v[t] = L1;
            ring_k[t] = K;
            __hip_atomic_store(&cnt, t, __ATOMIC_RELEASE,
                               __HIP_MEMORY_SCOPE_WORKGROUP);
          }
          bufB[u] = ld2(nx + (size_t)u * LSTRIDE);
          ++t;
        }
      }
    }
    if (g < ng) {
      bl_renorm2(B0, B1, L0, L1, K);
#pragma unroll
      for (int u = 0; u < 16; ++u) {
        bl_step2(B0, B1, L0, L1, sk0, sk1, bufA[u], 0.0, false, lane);
        if (lane == 49) {
          ring_v[t] = L1;
          ring_k[t] = K;
          __hip_atomic_store(&cnt, t, __ATOMIC_RELEASE,
                             __HIP_MEMORY_SCOPE_WORKGROUP);
        }
        ++t;
      }
      ++g;
    }
    {  // tail (<=15 steps)
      const int tstart = 1 + ng * 16;
      float2 bufT[15];
#pragma unroll
      for (int u = 0; u < 15; ++u) {
        int tt = tstart + u;
        if (tt > nsteps) tt = (nsteps > 0) ? nsteps : 1;
        bufT[u] = ld2(gp + (size_t)tt * LSTRIDE);
      }
#pragma unroll
      for (int u = 0; u < 15; ++u) {
        if (tstart + u <= nsteps) {
          if (u == 0) bl_renorm2(B0, B1, L0, L1, K);
          bl_step2(B0, B1, L0, L1, sk0, sk1, bufT[u], 0.0, false, lane);
          if (lane == 49) {
            ring_v[tstart + u] = L1;
            ring_k[tstart + u] = K;
            __hip_atomic_store(&cnt, tstart + u, __ATOMIC_RELEASE,
                               __HIP_MEMORY_SCOPE_WORKGROUP);
          }
        }
      }
    }

    spb = spb_sum(Lpb_ph + (size_t)b * GROWS, len, lane);  // after chain

    if (p0 < 100) { saB[p0] = B0; saL[p0] = L0; }
    if (p1 < 100) { saB[p1] = B1; saL[p1] = L1; }
    if (lane == 0) Kw2[0] = K;
  } else {
    // -------- wave 1: pairs 100..200 (+ masked 201..227) ------------------
    double B0 = 0.0, B1 = 0.0, L0 = 0.0, L1 = 0.0;
    int K = 0;
    int t = 1;
    while (t <= nsteps) {
      const int tgtc = ((t + 6) < nsteps) ? (t + 6) : nsteps;
      while (__hip_atomic_load(&cnt, __ATOMIC_ACQUIRE,
                               __HIP_MEMORY_SCOPE_WORKGROUP) < tgtc)
        __builtin_amdgcn_s_sleep(1);
      double bv[8];
      int bk[8];
#pragma unroll
      for (int j = 0; j < 8; ++j) {
        bv[j] = ring_v[t - 1 + j];   // entries beyond nsteps-1 unused
        bk[j] = ring_k[t - 1 + j];
      }
      const int emax = bl_renorm2(B0, B1, L0, L1, K);
      if (emax == 0) K = bk[0];      // adopt producer frame while band empty
      float2 fr[8];
#pragma unroll
      for (int j = 0; j < 8; ++j) {
        int tt = t + j;
        if (tt > nsteps) tt = nsteps;
        fr[j] = ld2(gp + (size_t)tt * LSTRIDE);
      }
#pragma unroll
      for (int u = 0; u < 8; ++u) {
        if (t + u <= nsteps) {
          int d = K - bk[u];
          if (d > 512) d = 512;      // self-correcting via next renorm
          if (d < -1022) d = -1022;
          const double sc = __hiloint2double((d + 1023) << 20, 0);
          bl_step2(B0, B1, L0, L1, sk0, sk1, fr[u], bv[u] * sc, true, lane);
        }
      }
      t += 8;
    }
    saB[p0] = B0; saL[p0] = L0;      // p0 in [100,226], no clash with w0
    saB[p1] = B1; saL[p1] = L1;
    if (lane == 0) Kw2[1] = K;
  }
  __syncthreads();
  if (threadIdx.x == 0) {
    const int iL = tl - 1, iB = tl;  // tl in [100,200]
    const int KL = (iL >= 100) ? Kw2[1] : Kw2[0];
    const int KB = (iB >= 100) ? Kw2[1] : Kw2[0];
    const double vL = saL[iL], vB = saB[iB];
    const int Kref = (KL < KB) ? KL : KB;
    int dL = Kref - KL; if (dL < -1022) dL = -1022;  // <= 0
    int dB = Kref - KB; if (dB < -1022) dB = -1022;
    const double A = vL * __hiloint2double((dL + 1023) << 20, 0) +
                     vB * __hiloint2double((dB + 1023) << 20, 0);
    float loss = (float)((double)Kref * LN2D - log(A) - (double)spb * LN2D);
    if (!(loss < 1e29f)) loss = 0.f;  // zero_infinity
    atomicAdd(out, loss / ((float)tl * 32.0f));
  }
}

// ========================= fallback path (R2, proven) ======================

__global__ __launch_bounds__(256) void softmax4_kernel(
    const float* __restrict__ x, float* __restrict__ p, int nrows) {
  int r = blockIdx.x * blockDim.x + threadIdx.x;
  if (r >= nrows) return;
  float4 v = *reinterpret_cast<const float4*>(x + (size_t)r * 4);
  float z0 = v.x * LOG2E, z1 = v.y * LOG2E, z2 = v.z * LOG2E, z3 = v.w * LOG2E;
  float m = fmaxf(fmaxf(z0, z1), fmaxf(z2, z3));
  float e0 = fexp2(z0 - m), e1 = fexp2(z1 - m);
  float e2 = fexp2(z2 - m), e3 = fexp2(z3 - m);
  float inv = 1.0f / (e0 + e1 + e2 + e3);
  float4 o;
  o.x = e0 * inv; o.y = e1 * inv; o.z = e2 * inv; o.w = e3 * inv;
  *reinterpret_cast<float4*>(p + (size_t)r * 4) = o;
}

__global__ __launch_bounds__(256) void softmax64_kernel(
    const float* __restrict__ x, float* __restrict__ p, int nrows) {
  int row = blockIdx.x * 4 + (threadIdx.x >> 6);
  int lane = threadIdx.x & 63;
  if (row >= nrows) return;
  float z = x[(size_t)row * 64 + lane] * LOG2E;
  float m = z;
#pragma unroll
  for (int off = 32; off >= 1; off >>= 1) m = fmaxf(m, __shfl_xor(m, off, 64));
  float e = fexp2(z - m);
  float s = e;
#pragma unroll
  for (int off = 32; off >= 1; off >>= 1) s += __shfl_xor(s, off, 64);
  p[(size_t)row * 64 + lane] = e * (1.0f / s);
}

template <int C, int S, int R>
__device__ __forceinline__ void ctc_chain_lin_fb(
    const float* __restrict__ p_b, const int* __restrict__ tgt_b,
    int len, int tl, float* __restrict__ out, double* sa) {
  constexpr int L = 2 * S + 1;
  const int lane = threadIdx.x;
  int idx[R];
  double skipm[R];
#pragma unroll
  for (int j = 0; j < R; ++j) {
    const int l = lane * R + j;
    int cls = 0;
    bool sk = false;
    if (l & 1) {
      const int s = (l - 1) >> 1;
      const int sc = (s < S) ? s : (S - 1);
      cls = tgt_b[sc];
      if (s >= 1 && s < S) sk = (cls != tgt_b[s - 1]);
    }
    idx[j] = cls * 4;
    skipm[j] = sk ? 1.0 : 0.0;
  }
  double alpha[R];
#pragma unroll
  for (int j = 0; j < R; ++j) {
    const int l = lane * R + j;
    alpha[j] = (l <= 1) ? (double)p_b[idx[j] >> 2] : 0.0;
  }
  int K = 0;
  const int cl = lane & (C - 1);
  float rv = p_b[(size_t)((1 < len - 1) ? 1 : (len - 1)) * C + cl];
  float pf[R];
#pragma unroll
  for (int j = 0; j < R; ++j)
    pf[j] = __int_as_float(__builtin_amdgcn_ds_bpermute(idx[j], __float_as_int(rv)));
  rv = p_b[(size_t)((2 < len - 1) ? 2 : (len - 1)) * C + cl];
  for (int t = 1; t < len; ++t) {
    if ((t & 31) == 0) {
      double m = alpha[0];
#pragma unroll
      for (int j = 1; j < R; ++j) m = fmax(m, alpha[j]);
#pragma unroll
      for (int off = 1; off < 64; off <<= 1) m = fmax(m, __shfl_xor(m, off, 64));
      const long long bits = __double_as_longlong(m);
      const int e = (int)((bits >> 52) & 0x7FF);
      if (e > 0) {
        const double sc = __longlong_as_double((long long)(2046 - e) << 52);
#pragma unroll
        for (int j = 0; j < R; ++j) alpha[j] *= sc;
        K += 1023 - e;
      }
    }
    const int tn = (t + 2 < len) ? (t + 2) : (len - 1);
    const float rvn = p_b[(size_t)tn * C + cl];
    float pfn[R];
#pragma unroll
    for (int j = 0; j < R; ++j)
      pfn[j] = __int_as_float(__builtin_amdgcn_ds_bpermute(idx[j], __float_as_int(rv)));
    double am1 = __shfl_up(alpha[R - 1], 1, 64);
    double am2 = __shfl_up(alpha[R - 2], 1, 64);
    if (lane == 0) { am1 = 0.0; am2 = 0.0; }
    double na[R];
#pragma unroll
    for (int j = 0; j < R; ++j) {
      const double a0 = alpha[j];
      const double a1 = (j >= 1) ? alpha[j - 1] : am1;
      const double a2 = (j >= 2) ? alpha[j - 2] : ((j == 1) ? am1 : am2);
      double s = a0 + a1;
      s = fma(skipm[j], a2, s);
      na[j] = (double)pf[j] * s;
    }
#pragma unroll
    for (int j = 0; j < R; ++j) alpha[j] = na[j];
#pragma unroll
    for (int j = 0; j < R; ++j) pf[j] = pfn[j];
    rv = rvn;
  }
#pragma unroll
  for (int j = 0; j < R; ++j) {
    const int l = lane * R + j;
    if (l < L) sa[l] = alpha[j];
  }
  __syncthreads();
  if (lane == 0) {
    const double a = sa[2 * tl - 1] + sa[2 * tl];
    float loss = (float)((double)K * LN2D - log(a));
    if (!(loss < 1e29f)) loss = 0.0f;
    atomicAdd(out, loss / ((float)tl * 32.0f));
  }
}

__global__ __launch_bounds__(64) void ctc_chains_fb_kernel(
    const float* __restrict__ p_err, const float* __restrict__ p_ph,
    const int* __restrict__ err_tgt, const int* __restrict__ ph_tgt,
    const int* __restrict__ err_il, const int* __restrict__ ph_il,
    const int* __restrict__ err_tl, const int* __restrict__ ph_tl,
    float* __restrict__ out) {
  __shared__ double sa[512];
  const int T = 2000;
  const int blk = blockIdx.x;
  if (blk < 32) {
    const int b = blk;
    int len = err_il[b]; if (len > T) len = T;
    ctc_chain_lin_fb<4, 50, 2>(p_err + (size_t)b * T * 4, err_tgt + b * 50, len,
                               err_tl[b], out, sa);
  } else {
    const int b = blk - 32;
    int len = ph_il[b]; if (len > T) len = T;
    ctc_chain_lin_fb<64, 200, 7>(p_ph + (size_t)b * T * 64, ph_tgt + b * 200,
                                 len, ph_tl[b], out, sa);
  }
}

// ========================= launch ==========================================

extern "C" void kernel_launch(void* const* d_in, const int* in_sizes, int n_in,
                              void* d_out, int out_size, void* d_ws,
                              size_t ws_size, hipStream_t stream) {
  const float* err_logits = (const float*)d_in[0];
  const float* ph_logits  = (const float*)d_in[1];
  const int* err_tgt = (const int*)d_in[2];
  const int* ph_tgt  = (const int*)d_in[3];
  const int* err_il  = (const int*)d_in[4];
  const int* ph_il   = (const int*)d_in[5];
  const int* err_tl  = (const int*)d_in[6];
  const int* ph_tl   = (const int*)d_in[7];
  float* out = (float*)d_out;

  const size_t gph = (size_t)32 * GROWS * 256;  // floats, 66.6 MB
  const size_t lpb = (size_t)32 * GROWS;        // floats, per task
  const size_t need = (gph + 2 * lpb) * sizeof(float);

  if (ws_size >= need) {
    float* Gph = (float*)d_ws;
    float* Lpb_ph = Gph + gph;
    float* Lpb_er = Lpb_ph + lpb;
    // gather zeroes *out (chain kernel is stream-ordered after it)
    gather_ph_kernel<<<dim3(63, 32), 256, 0, stream>>>(
        ph_logits, err_logits, ph_tgt, Gph, Lpb_ph, Lpb_er, out);
    ctc_chains_split_kernel<<<64, 128, 0, stream>>>(
        Gph, err_logits, ph_tgt, err_tgt, err_il, ph_il, err_tl, ph_tl,
        Lpb_ph, Lpb_er, out);
  } else {
    (void)hipMemsetAsync(d_out, 0, sizeof(float), stream);
    const int B = 32, T = 2000;
    const int rows = B * T;
    float* p_err = (float*)d_ws;
    float* p_ph  = p_err + (size_t)rows * 4;
    softmax4_kernel<<<(rows + 255) / 256, 256, 0, stream>>>(err_logits, p_err, rows);
    softmax64_kernel<<<(rows + 3) / 4, 256, 0, stream>>>(ph_logits, p_ph, rows);
    ctc_chains_fb_kernel<<<64, 64, 0, stream>>>(p_err, p_ph, err_tgt, ph_tgt,
                                                err_il, ph_il, err_tl, ph_tl, out);
  }
}

// Round 14
// 192.629 us; speedup vs baseline: 1.7341x; 1.7341x over previous
//
#include <hip/hip_runtime.h>
#include <math.h>

// ---------------------------------------------------------------------------
// Dual CTC loss forward, linear-probability fp64 recursion, beta-normalized
// B/L split form (validated R6), R9-proven interleaved register prefetch.
// R22: slim gather + Ger  |  R9-literal chain for BOTH paths.
//  R21 post-mortem: band-split regressed (251us) — per-step LDS publish on
//  the producer's serial path. All parallelization ideas now closed (time-
//  split null x4, band-split regressed, fusion poisoned, f32 wrong, packed
//  f64 absent). Budget ledger: R9 = gather+Ger(50) + chain(101) = 151;
//  R19 = slim gather(32) + chain(117.6) = 150 — the chain's +17 appeared
//  exactly when the error path switched from Ger-loads to inline-f. Untested
//  combination: slim gather THAT ALSO WRITES GER (error e-values already
//  computed for Lpb_er; +17MB writes ~ +5us) + R9-verbatim chain (Ger-based
//  error path, proven to co-compile at 101).
//  error task:   B=32, T=2000, C=4,  S=50   (Ger r-values, 1 float/lane)
//  phoneme task: B=32, T=2000, C=64, S=200  (Gph r-values, float4/lane)
// Falls back to the R2 proven path if ws too small.
// ---------------------------------------------------------------------------

static constexpr float  LOG2E = 1.4426950408889634f;
static constexpr double LN2D  = 0.6931471805599453;
static constexpr int GROWS = 2032;  // padded rows per chain

#define DPP_WAVE_SHR1   0x138
#define DPP_ROW_SHR(n)  (0x110 | (n))
#define DPP_ROW_BCAST15 0x142
#define DPP_ROW_BCAST31 0x143

__device__ __forceinline__ float fexp2(float x) {
  return __builtin_amdgcn_exp2f(x);
}
__device__ __forceinline__ float flog2(float x) {
  return __builtin_amdgcn_logf(x);
}

// prev-lane value (lane i gets lane i-1; lane 0 gets 0.0) — pure VALU
__device__ __forceinline__ double dpp_shr1_f64(double x) {
  int lo = __double2loint(x), hi = __double2hiint(x);
  lo = __builtin_amdgcn_update_dpp(0, lo, DPP_WAVE_SHR1, 0xf, 0xf, true);
  hi = __builtin_amdgcn_update_dpp(0, hi, DPP_WAVE_SHR1, 0xf, 0xf, true);
  return __hiloint2double(hi, lo);
}

__device__ __forceinline__ int imax2(int a, int b) { return a > b ? a : b; }

__device__ __forceinline__ int wave_imax(int v) {
  v = imax2(v, __builtin_amdgcn_update_dpp(0, v, DPP_ROW_SHR(1), 0xf, 0xf, true));
  v = imax2(v, __builtin_amdgcn_update_dpp(0, v, DPP_ROW_SHR(2), 0xf, 0xf, true));
  v = imax2(v, __builtin_amdgcn_update_dpp(0, v, DPP_ROW_SHR(4), 0xf, 0xf, true));
  v = imax2(v, __builtin_amdgcn_update_dpp(0, v, DPP_ROW_SHR(8), 0xf, 0xf, true));
  v = imax2(v, __builtin_amdgcn_update_dpp(0, v, DPP_ROW_BCAST15, 0xf, 0xf, true));
  v = imax2(v, __builtin_amdgcn_update_dpp(0, v, DPP_ROW_BCAST31, 0xf, 0xf, true));
  return __builtin_amdgcn_readlane(v, 63);
}

// wait lgkmcnt(0) only (vmcnt=63, exp=7): gfx9 encode 0xC07F = 49279
__device__ __forceinline__ void wait_lgkm0() {
  __builtin_amdgcn_sched_barrier(0);
  __builtin_amdgcn_s_waitcnt(49279);
  __builtin_amdgcn_sched_barrier(0);
}

// ========================= fast path =======================================

// Slim gather + Ger: phoneme r-values, error r-values, both Lpb, out=0.
//  grid(63, 32), 256 thr.
//  Phoneme: wave wv handles 8 rows t=(bx*4+wv)*8+u (R13-proven).
//  Error:   wave wv handles 8 rows t=bx*32+wv*8+u; per row broadcast float4,
//           Ger[t][lane] = (lane<50) ? e_{c1[lane]}/e0 : 0; lane0 -> Lpb_er.
__global__ __launch_bounds__(256) void gather_all_kernel(
    const float* __restrict__ ph_logits, const float* __restrict__ err_logits,
    const int* __restrict__ ph_tgt, const int* __restrict__ err_tgt,
    float* __restrict__ Gph, float* __restrict__ Ger,
    float* __restrict__ Lpb_ph, float* __restrict__ Lpb_er,
    float* __restrict__ out) {
  const int bx = blockIdx.x, b = blockIdx.y;
  const int tid = threadIdx.x;
  const int lane = tid & 63, wv = tid >> 6;

  if (bx == 0 && b == 0 && tid == 0) *out = 0.f;  // chain kernel comes after

  // ---- error: 8 rows per wave, r-values + Lpb ----
  {
    const int c1 = err_tgt[b * 50 + ((lane < 50) ? lane : 49)];
    const float msk = (lane < 50) ? 1.0f : 0.0f;
    const int t0 = bx * 32 + wv * 8;
#pragma unroll
    for (int u = 0; u < 8; ++u) {
      const int t = t0 + u;
      const int tc = (t < 2000) ? t : 1999;
      const float4 v =
          *(const float4*)(err_logits + ((size_t)b * 2000 + tc) * 4);
      const float z0 = v.x * LOG2E;
      const float e0 = fexp2(z0);
      const float e1 = fexp2(v.y * LOG2E);
      const float e2 = fexp2(v.z * LOG2E);
      const float e3 = fexp2(v.w * LOG2E);
      const float num = (c1 == 1) ? e1 : (c1 == 2) ? e2 : e3;
      if (t < 2000) {
        Ger[((size_t)b * GROWS + t) * 64 + lane] = msk * (num / e0);
        if (lane == 0)
          Lpb_er[(size_t)b * GROWS + t] = z0 - flog2(e0 + e1 + e2 + e3);
      }
    }
  }

  // ---- phoneme: 8 rows per wave (R13-proven) ----
  const int* tb = ph_tgt + b * 200;
  int idx[4];
  float msk[4];
#pragma unroll
  for (int k = 0; k < 4; ++k) {
    const int si = lane * 4 + k;
    const int cls = (si < 200) ? tb[si] : 0;
    idx[k] = cls << 2;
    msk[k] = (si < 200) ? 1.0f : 0.0f;
  }
  const int t0 = (bx * 4 + wv) * 8;
  float z[8], e[8], s[8];
#pragma unroll
  for (int u = 0; u < 8; ++u) {
    const int t = t0 + u;
    const int tc = (t < 2000) ? t : 1999;
    z[u] = ph_logits[((size_t)b * 2000 + tc) * 64 + lane] * LOG2E;
    e[u] = fexp2(z[u]);
    s[u] = e[u];
  }
#pragma unroll
  for (int off = 32; off >= 1; off >>= 1) {
#pragma unroll
    for (int u = 0; u < 8; ++u) s[u] += __shfl_xor(s[u], off, 64);
  }
#pragma unroll
  for (int u = 0; u < 8; ++u) {
    const int t = t0 + u;
    if (t < 2000) {
      const float e0 = __int_as_float(
          __builtin_amdgcn_readlane(__float_as_int(e[u]), 0));
      const float inv0 = 1.0f / e0;
      float o[4];
#pragma unroll
      for (int k = 0; k < 4; ++k) {
        const float v = __int_as_float(
            __builtin_amdgcn_ds_bpermute(idx[k], __float_as_int(e[u])));
        o[k] = msk[k] * v * inv0;
      }
      *(float4*)(Gph + ((size_t)b * GROWS + t) * 256 + lane * 4) =
          make_float4(o[0], o[1], o[2], o[3]);
      if (lane == 0)  // lane 0's z is z0*log2e
        Lpb_ph[(size_t)b * GROWS + t] = z[u] - flog2(s[u]);
    }
  }
}

template <int P> struct RowP { float v[P]; };

template <int P>
__device__ __forceinline__ RowP<P> load_rowp(const float* p) {
  RowP<P> r;
  if constexpr (P == 4) {
    const float4 a = *(const float4*)p;
    r.v[0] = a.x; r.v[1] = a.y; r.v[2] = a.z; r.v[3] = a.w;
  } else {
    r.v[0] = *p;
  }
  return r;
}

template <int P>
__device__ __forceinline__ void bl_renorm(double (&B)[P], double (&L)[P],
                                          int& K) {
  double mm = B[0];
#pragma unroll
  for (int k = 0; k < P; ++k) mm = fmax(fmax(mm, B[k]), L[k]);
  const int ex = (__double2hiint(mm) >> 20) & 0x7ff;
  const int emax = wave_imax(ex);
  if (emax > 0) {
    int d = 1523 - emax;            // pin band max to ~2^500
    if (d > 1023) d = 1023;         // keep 2^d normal (beta can grow too)
    if (d < -1022) d = -1022;
    const double sc = __hiloint2double((d + 1023) << 20, 0);
#pragma unroll
    for (int k = 0; k < P; ++k) { B[k] *= sc; L[k] *= sc; }
    K += d;
  }
}

template <int P>
__device__ __forceinline__ void bl_step(double (&B)[P], double (&L)[P],
                                        const double (&skipm)[P],
                                        const RowP<P>& f) {
  const double Lm1 = dpp_shr1_f64(L[P - 1]);
  double nB[P], nL[P];
#pragma unroll
  for (int k = 0; k < P; ++k) {
    const double Lp = (k >= 1) ? L[k - 1] : Lm1;
    nB[k] = B[k] + Lp;
    nL[k] = (double)f.v[k] * fma(skipm[k], Lp, B[k] + L[k]);
  }
#pragma unroll
  for (int k = 0; k < P; ++k) { B[k] = nB[k]; L[k] = nL[k]; }
}

// One wave advances one chain; lane owns pairs s = lane*P..lane*P+P-1.
// R9-literal: 16-row register double-buffer, interleaved per-step refill,
// wave-local LDS readout (single-wave block).
template <int P, int S>
__device__ __forceinline__ void chain_bl5(
    const float* __restrict__ Glab,  // [GROWS][64*P] r-values
    const float* __restrict__ Lpb,   // [GROWS] log2(pb)
    const int* __restrict__ tb, int len, int tl,
    float* __restrict__ out, double* sa) {
  constexpr int LSTRIDE = 64 * P;  // floats per row
  const int lane = threadIdx.x;

  // spb = sum_{t<len} log2(pb(t)), lane-parallel, unrolled x8
  float spb = 0.f;
  for (int t0 = lane; t0 < len; t0 += 512) {
#pragma unroll
    for (int u = 0; u < 8; ++u) {
      const int t = t0 + u * 64;
      const int tc = (t < len) ? t : 0;        // always-valid address
      const float v = Lpb[tc];
      spb += (t < len) ? v : 0.0f;             // cndmask, no branch
    }
  }
#pragma unroll
  for (int off = 32; off >= 1; off >>= 1) spb += __shfl_xor(spb, off, 64);

  double skipm[P];
#pragma unroll
  for (int k = 0; k < P; ++k) {
    const int s = lane * P + k;
    skipm[k] = (s >= 1 && s < S && tb[s] != tb[s - 1]) ? 1.0 : 0.0;
  }

  double B[P], L[P];
#pragma unroll
  for (int k = 0; k < P; ++k) { B[k] = 0.0; L[k] = 0.0; }
  {
    const float r0 = Glab[0];  // lane0 slot0 = r_{tgt[0]}(0)
    if (lane == 0) { B[0] = 1.0; L[0] = (double)r0; }
  }
  int K = 0;

  const float* gp = Glab + lane * P;     // row t at gp + t*LSTRIDE
  const int ngroups = (len - 1) / 16;    // full groups: rows 1+16g..16+16g

  RowP<P> bufA[16], bufB[16];
  if (ngroups >= 1) {
    const float* rb = gp + (size_t)1 * LSTRIDE;
#pragma unroll
    for (int u = 0; u < 16; ++u)
      bufA[u] = load_rowp<P>(rb + (size_t)u * LSTRIDE);
  }
  if (ngroups >= 2) {
    const float* rb = gp + (size_t)17 * LSTRIDE;
#pragma unroll
    for (int u = 0; u < 16; ++u)
      bufB[u] = load_rowp<P>(rb + (size_t)u * LSTRIDE);
  }

  int g = 0;
  for (; g + 2 <= ngroups; g += 2) {
    // ---- group g from bufA; refill bufA with group g+2 (clamped-safe) ----
    {
      bl_renorm<P>(B, L, K);
      const int gn = (g + 2 < ngroups) ? (g + 2) : 0;  // clamp: rows 1..16,
      const float* nx = gp + (size_t)(1 + gn * 16) * LSTRIDE;  // never consumed
#pragma unroll
      for (int u = 0; u < 16; ++u) {
        bl_step<P>(B, L, skipm, bufA[u]);
        bufA[u] = load_rowp<P>(nx + (size_t)u * LSTRIDE);
      }
    }
    // ---- group g+1 from bufB; refill bufB with group g+3 ----
    {
      bl_renorm<P>(B, L, K);
      const int gn = (g + 3 < ngroups) ? (g + 3) : 0;
      const float* nx = gp + (size_t)(1 + gn * 16) * LSTRIDE;
#pragma unroll
      for (int u = 0; u < 16; ++u) {
        bl_step<P>(B, L, skipm, bufB[u]);
        bufB[u] = load_rowp<P>(nx + (size_t)u * LSTRIDE);
      }
    }
  }
  if (g < ngroups) {  // odd ngroups: last full group sits in bufA
    bl_renorm<P>(B, L, K);
#pragma unroll
    for (int u = 0; u < 16; ++u) bl_step<P>(B, L, skipm, bufA[u]);
    ++g;
  }

  // tail (<16 steps): batch-prefetch into registers, one latency hit total.
  {
    const int tstart = 1 + ngroups * 16;
    RowP<P> bufT[15];
#pragma unroll
    for (int u = 0; u < 15; ++u) {
      int t = tstart + u;
      if (t > len - 1) t = len - 1;            // always-valid address
      bufT[u] = load_rowp<P>(gp + (size_t)t * LSTRIDE);
    }
#pragma unroll
    for (int u = 0; u < 15; ++u) {
      const int t = tstart + u;
      if (t < len) {
        if (u == 0) bl_renorm<P>(B, L, K);     // (t-1) = 16*ngroups == 0 mod 16
        bl_step<P>(B, L, skipm, bufT[u]);
      }
    }
  }

  // readout: alpha[2tl-1] = L[tl-1], alpha[2tl] = B[tl] (wave-local LDS)
  double* saB = sa;
  double* saL = sa + 64 * P;
#pragma unroll
  for (int k = 0; k < P; ++k) {
    saB[lane * P + k] = B[k];
    saL[lane * P + k] = L[k];
  }
  wait_lgkm0();  // drain ds_writes; single-wave block, no barrier needed
  if (lane == 0) {
    const double a = saL[tl - 1] + saB[tl];
    float loss = (float)((double)K * LN2D - log(a) - (double)spb * LN2D);
    if (!(loss < 1e29f)) loss = 0.f;  // zero_infinity
    atomicAdd(out, loss / ((float)tl * 32.0f));
  }
}

// R9-literal chain kernel: 64 blocks x 64 thr.
__global__ __launch_bounds__(64) void ctc_chains_reg_kernel(
    const float* __restrict__ Gph, const float* __restrict__ Ger,
    const float* __restrict__ Lpb_ph, const float* __restrict__ Lpb_er,
    const int* __restrict__ err_tgt, const int* __restrict__ ph_tgt,
    const int* __restrict__ err_il, const int* __restrict__ ph_il,
    const int* __restrict__ err_tl, const int* __restrict__ ph_tl,
    float* __restrict__ out) {
  __shared__ double sa[512];
  const int blk = blockIdx.x;
  if (blk < 32) {
    int len = err_il[blk]; if (len > 2000) len = 2000;
    chain_bl5<1, 50>(Ger + (size_t)blk * GROWS * 64,
                     Lpb_er + (size_t)blk * GROWS, err_tgt + blk * 50, len,
                     err_tl[blk], out, sa);
  } else {
    const int b = blk - 32;
    int len = ph_il[b]; if (len > 2000) len = 2000;
    chain_bl5<4, 200>(Gph + (size_t)b * GROWS * 256,
                      Lpb_ph + (size_t)b * GROWS, ph_tgt + b * 200, len,
                      ph_tl[b], out, sa);
  }
}

// ========================= fallback path (R2, proven) ======================

__global__ __launch_bounds__(256) void softmax4_kernel(
    const float* __restrict__ x, float* __restrict__ p, int nrows) {
  int r = blockIdx.x * blockDim.x + threadIdx.x;
  if (r >= nrows) return;
  float4 v = *reinterpret_cast<const float4*>(x + (size_t)r * 4);
  float z0 = v.x * LOG2E, z1 = v.y * LOG2E, z2 = v.z * LOG2E, z3 = v.w * LOG2E;
  float m = fmaxf(fmaxf(z0, z1), fmaxf(z2, z3));
  float e0 = fexp2(z0 - m), e1 = fexp2(z1 - m);
  float e2 = fexp2(z2 - m), e3 = fexp2(z3 - m);
  float inv = 1.0f / (e0 + e1 + e2 + e3);
  float4 o;
  o.x = e0 * inv; o.y = e1 * inv; o.z = e2 * inv; o.w = e3 * inv;
  *reinterpret_cast<float4*>(p + (size_t)r * 4) = o;
}

__global__ __launch_bounds__(256) void softmax64_kernel(
    const float* __restrict__ x, float* __restrict__ p, int nrows) {
  int row = blockIdx.x * 4 + (threadIdx.x >> 6);
  int lane = threadIdx.x & 63;
  if (row >= nrows) return;
  float z = x[(size_t)row * 64 + lane] * LOG2E;
  float m = z;
#pragma unroll
  for (int off = 32; off >= 1; off >>= 1) m = fmaxf(m, __shfl_xor(m, off, 64));
  float e = fexp2(z - m);
  float s = e;
#pragma unroll
  for (int off = 32; off >= 1; off >>= 1) s += __shfl_xor(s, off, 64);
  p[(size_t)row * 64 + lane] = e * (1.0f / s);
}

template <int C, int S, int R>
__device__ __forceinline__ void ctc_chain_lin_fb(
    const float* __restrict__ p_b, const int* __restrict__ tgt_b,
    int len, int tl, float* __restrict__ out, double* sa) {
  constexpr int L = 2 * S + 1;
  const int lane = threadIdx.x;
  int idx[R];
  double skipm[R];
#pragma unroll
  for (int j = 0; j < R; ++j) {
    const int l = lane * R + j;
    int cls = 0;
    bool sk = false;
    if (l & 1) {
      const int s = (l - 1) >> 1;
      const int sc = (s < S) ? s : (S - 1);
      cls = tgt_b[sc];
      if (s >= 1 && s < S) sk = (cls != tgt_b[s - 1]);
    }
    idx[j] = cls * 4;
    skipm[j] = sk ? 1.0 : 0.0;
  }
  double alpha[R];
#pragma unroll
  for (int j = 0; j < R; ++j) {
    const int l = lane * R + j;
    alpha[j] = (l <= 1) ? (double)p_b[idx[j] >> 2] : 0.0;
  }
  int K = 0;
  const int cl = lane & (C - 1);
  float rv = p_b[(size_t)((1 < len - 1) ? 1 : (len - 1)) * C + cl];
  float pf[R];
#pragma unroll
  for (int j = 0; j < R; ++j)
    pf[j] = __int_as_float(__builtin_amdgcn_ds_bpermute(idx[j], __float_as_int(rv)));
  rv = p_b[(size_t)((2 < len - 1) ? 2 : (len - 1)) * C + cl];
  for (int t = 1; t < len; ++t) {
    if ((t & 31) == 0) {
      double m = alpha[0];
#pragma unroll
      for (int j = 1; j < R; ++j) m = fmax(m, alpha[j]);
#pragma unroll
      for (int off = 1; off < 64; off <<= 1) m = fmax(m, __shfl_xor(m, off, 64));
      const long long bits = __double_as_longlong(m);
      const int e = (int)((bits >> 52) & 0x7FF);
      if (e > 0) {
        const double sc = __longlong_as_double((long long)(2046 - e) << 52);
#pragma unroll
        for (int j = 0; j < R; ++j) alpha[j] *= sc;
        K += 1023 - e;
      }
    }
    const int tn = (t + 2 < len) ? (t + 2) : (len - 1);
    const float rvn = p_b[(size_t)tn * C + cl];
    float pfn[R];
#pragma unroll
    for (int j = 0; j < R; ++j)
      pfn[j] = __int_as_float(__builtin_amdgcn_ds_bpermute(idx[j], __float_as_int(rv)));
    double am1 = __shfl_up(alpha[R - 1], 1, 64);
    double am2 = __shfl_up(alpha[R - 2], 1, 64);
    if (lane == 0) { am1 = 0.0; am2 = 0.0; }
    double na[R];
#pragma unroll
    for (int j = 0; j < R; ++j) {
      const double a0 = alpha[j];
      const double a1 = (j >= 1) ? alpha[j - 1] : am1;
      const double a2 = (j >= 2) ? alpha[j - 2] : ((j == 1) ? am1 : am2);
      double s = a0 + a1;
      s = fma(skipm[j], a2, s);
      na[j] = (double)pf[j] * s;
    }
#pragma unroll
    for (int j = 0; j < R; ++j) alpha[j] = na[j];
#pragma unroll
    for (int j = 0; j < R; ++j) pf[j] = pfn[j];
    rv = rvn;
  }
#pragma unroll
  for (int j = 0; j < R; ++j) {
    const int l = lane * R + j;
    if (l < L) sa[l] = alpha[j];
  }
  __syncthreads();
  if (lane == 0) {
    const double a = sa[2 * tl - 1] + sa[2 * tl];
    float loss = (float)((double)K * LN2D - log(a));
    if (!(loss < 1e29f)) loss = 0.0f;
    atomicAdd(out, loss / ((float)tl * 32.0f));
  }
}

__global__ __launch_bounds__(64) void ctc_chains_fb_kernel(
    const float* __restrict__ p_err, const float* __restrict__ p_ph,
    const int* __restrict__ err_tgt, const int* __restrict__ ph_tgt,
    const int* __restrict__ err_il, const int* __restrict__ ph_il,
    const int* __restrict__ err_tl, const int* __restrict__ ph_tl,
    float* __restrict__ out) {
  __shared__ double sa[512];
  const int T = 2000;
  const int blk = blockIdx.x;
  if (blk < 32) {
    const int b = blk;
    int len = err_il[b]; if (len > T) len = T;
    ctc_chain_lin_fb<4, 50, 2>(p_err + (size_t)b * T * 4, err_tgt + b * 50, len,
                               err_tl[b], out, sa);
  } else {
    const int b = blk - 32;
    int len = ph_il[b]; if (len > T) len = T;
    ctc_chain_lin_fb<64, 200, 7>(p_ph + (size_t)b * T * 64, ph_tgt + b * 200,
                                 len, ph_tl[b], out, sa);
  }
}

// ========================= launch ==========================================

extern "C" void kernel_launch(void* const* d_in, const int* in_sizes, int n_in,
                              void* d_out, int out_size, void* d_ws,
                              size_t ws_size, hipStream_t stream) {
  const float* err_logits = (const float*)d_in[0];
  const float* ph_logits  = (const float*)d_in[1];
  const int* err_tgt = (const int*)d_in[2];
  const int* ph_tgt  = (const int*)d_in[3];
  const int* err_il  = (const int*)d_in[4];
  const int* ph_il   = (const int*)d_in[5];
  const int* err_tl  = (const int*)d_in[6];
  const int* ph_tl   = (const int*)d_in[7];
  float* out = (float*)d_out;

  const size_t gph = (size_t)32 * GROWS * 256;  // 66.6 MB
  const size_t ger = (size_t)32 * GROWS * 64;   // 16.6 MB
  const size_t lpb = (size_t)32 * GROWS;        // per task
  const size_t need = (gph + ger + 2 * lpb) * sizeof(float);

  if (ws_size >= need) {
    float* Gph = (float*)d_ws;
    float* Ger = Gph + gph;
    float* Lpb_ph = Ger + ger;
    float* Lpb_er = Lpb_ph + lpb;
    // gather zeroes *out (chain kernel is stream-ordered after it)
    gather_all_kernel<<<dim3(63, 32), 256, 0, stream>>>(
        ph_logits, err_logits, ph_tgt, err_tgt, Gph, Ger, Lpb_ph, Lpb_er,
        out);
    ctc_chains_reg_kernel<<<64, 64, 0, stream>>>(Gph, Ger, Lpb_ph, Lpb_er,
                                                 err_tgt, ph_tgt, err_il,
                                                 ph_il, err_tl, ph_tl, out);
  } else {
    (void)hipMemsetAsync(d_out, 0, sizeof(float), stream);
    const int B = 32, T = 2000;
    const int rows = B * T;
    float* p_err = (float*)d_ws;
    float* p_ph  = p_err + (size_t)rows * 4;
    softmax4_kernel<<<(rows + 255) / 256, 256, 0, stream>>>(err_logits, p_err, rows);
    softmax64_kernel<<<(rows + 3) / 4, 256, 0, stream>>>(ph_logits, p_ph, rows);
    ctc_chains_fb_kernel<<<64, 64, 0, stream>>>(p_err, p_ph, err_tgt, ph_tgt,
                                                err_il, ph_il, err_tl, ph_tl, out);
  }
}